// Round 1
// baseline (287.280 us; speedup 1.0000x reference)
//
#include <hip/hip_runtime.h>
#include <hip/hip_bf16.h>

#define NBATCH 4
#define NN 4096
#define NF 128
#define NU 64
#define CHUNK 256
#define NCHUNK (NN / CHUNK)   // 16
#define LEAKY 0.2f

// ---------------------------------------------------------------------------
// k1: h[b,n,u] = sum_f x[b,n,f] * W[f,u];  f1 = h.a1, f2 = h.a2 (wave reduce)
// block = 256 threads (4 waves), 64 rows per block
// ---------------------------------------------------------------------------
__global__ __launch_bounds__(256) void k1_h(
    const float* __restrict__ x, const float* __restrict__ W,
    const float* __restrict__ a,
    float* __restrict__ h, float* __restrict__ f1, float* __restrict__ f2) {
  __shared__ float Ws[NF][NU];   // 32 KB
  __shared__ float xs[64][NF];   // 32 KB
  __shared__ float a1s[NU], a2s[NU];
  int tid = threadIdx.x;
  for (int k = tid; k < NF * NU; k += 256) ((float*)Ws)[k] = W[k];
  if (tid < NU) { a1s[tid] = a[tid]; a2s[tid] = a[NU + tid]; }
  int row0 = blockIdx.x * 64;   // flat row in [0, B*N)
  for (int k = tid; k < 64 * NF; k += 256)
    ((float*)xs)[k] = x[(size_t)row0 * NF + k];
  __syncthreads();
  int u = tid & 63;
  int wv = tid >> 6;            // wave id 0..3
  for (int rr = 0; rr < 16; ++rr) {
    int lr = wv * 16 + rr;
    float acc = 0.f;
#pragma unroll 16
    for (int f = 0; f < NF; ++f) acc += xs[lr][f] * Ws[f][u];
    int grow = row0 + lr;
    h[(size_t)grow * NU + u] = acc;
    float p1 = acc * a1s[u], p2 = acc * a2s[u];
#pragma unroll
    for (int off = 32; off >= 1; off >>= 1) {
      p1 += __shfl_xor(p1, off, 64);
      p2 += __shfl_xor(p2, off, 64);
    }
    if (u == 0) { f1[grow] = p1; f2[grow] = p2; }
  }
}

// ---------------------------------------------------------------------------
// k2: rank-by-counting "sort" of f2 per batch. block = (batch, chunk of 256 j)
// rank = #{k : f2[k] < my  ||  (f2[k]==my && k<j)}  -> perfect permutation
// scatter sorted f2, exp weights, permutation
// ---------------------------------------------------------------------------
__global__ __launch_bounds__(256) void k2_rank(
    const float* __restrict__ f2, int* __restrict__ perm,
    float* __restrict__ f2s, float* __restrict__ whi, float* __restrict__ wlo) {
  __shared__ float fs[NN];       // 16 KB
  int b = blockIdx.x >> 4;
  int chunk = blockIdx.x & 15;
  int tid = threadIdx.x;
  const float* f2b = f2 + b * NN;
  for (int k = tid; k < NN; k += 256) fs[k] = f2b[k];
  __syncthreads();
  int j = chunk * 256 + tid;
  float my = fs[j];
  int rank = 0;
#pragma unroll 8
  for (int k = 0; k < NN; ++k) {
    float v = fs[k];
    rank += (v < my) || (v == my && k < j);
  }
  int o = b * NN + rank;
  perm[o] = j;
  f2s[o] = my;
  whi[o] = expf(my);
  wlo[o] = expf(LEAKY * my);
}

// ---------------------------------------------------------------------------
// k3: chunked inclusive scan (within chunk) of
//   hi: sum_k exp(f2s[k]) * h[perm[k]][u]     (threads 0..63)
//   lo: sum_k exp(0.2 f2s[k]) * h[perm[k]][u] (threads 64..127)
// plus scalar denominators (lane u==0). Chunk totals -> CT (pre-scan).
// ---------------------------------------------------------------------------
__global__ __launch_bounds__(128) void k3_scan(
    const float* __restrict__ h, const int* __restrict__ perm,
    const float* __restrict__ whi, const float* __restrict__ wlo,
    float* __restrict__ LPhi, float* __restrict__ LPlo,
    float* __restrict__ LPshi, float* __restrict__ LPslo,
    float* __restrict__ CThi, float* __restrict__ CTlo,
    float* __restrict__ CTshi, float* __restrict__ CTslo) {
  __shared__ int pj[CHUNK];
  __shared__ float wh[CHUNK], wl[CHUNK];
  int b = blockIdx.x >> 4;
  int chunk = blockIdx.x & 15;
  int k0 = b * NN + chunk * CHUNK;   // global sorted index base
  int tid = threadIdx.x;
  for (int k = tid; k < CHUNK; k += 128) {
    pj[k] = perm[k0 + k];
    wh[k] = whi[k0 + k];
    wl[k] = wlo[k0 + k];
  }
  __syncthreads();
  int u = tid & 63;
  bool hi = tid < 64;
  float* LP = hi ? LPhi : LPlo;
  float* LPs = hi ? LPshi : LPslo;
  const float* hb = h + (size_t)b * NN * NU;
  float acc = 0.f, sacc = 0.f;
  for (int k = 0; k < CHUNK; ++k) {
    float w = hi ? wh[k] : wl[k];
    int j = pj[k];
    acc += w * hb[(size_t)j * NU + u];
    LP[(size_t)(k0 + k) * NU + u] = acc;
    if (u == 0) { sacc += w; LPs[k0 + k] = sacc; }
  }
  float* CT = hi ? CThi : CTlo;
  CT[(size_t)(b * 17 + chunk) * NU + u] = acc;
  if (u == 0) (hi ? CTshi : CTslo)[b * 17 + chunk] = sacc;
}

// ---------------------------------------------------------------------------
// k3b: exclusive scan of the 16 chunk totals, in place; total at slot [16].
// one block.
// ---------------------------------------------------------------------------
__global__ __launch_bounds__(192) void k3b_ct(
    float* __restrict__ CThi, float* __restrict__ CTlo,
    float* __restrict__ CTshi, float* __restrict__ CTslo) {
  int tid = threadIdx.x;
  if (tid < 128) {
    int u = tid & 63;
    float* CT = (tid < 64) ? CThi : CTlo;
    for (int b = 0; b < NBATCH; ++b) {
      float acc = 0.f;
      for (int c = 0; c < NCHUNK; ++c) {
        size_t idx = (size_t)(b * 17 + c) * NU + u;
        float cur = CT[idx];
        CT[idx] = acc;
        acc += cur;
      }
      CT[(size_t)(b * 17 + 16) * NU + u] = acc;
    }
  } else if (tid < 136) {
    int t2 = tid - 128;
    int b = t2 >> 1;
    float* CTs = (t2 & 1) ? CTslo : CTshi;
    float acc = 0.f;
    for (int c = 0; c < NCHUNK; ++c) {
      float cur = CTs[b * 17 + c];
      CTs[b * 17 + c] = acc;
      acc += cur;
    }
    CTs[b * 17 + 16] = acc;
  }
}

// ---------------------------------------------------------------------------
// k4: per output row: binary search threshold t, gather prefix rows, combine.
// block = 256 threads = 4 waves = 4 rows; lane u handles channel u.
// ---------------------------------------------------------------------------
__global__ __launch_bounds__(256) void k4_out(
    const float* __restrict__ f1, const float* __restrict__ f2s,
    const float* __restrict__ LPhi, const float* __restrict__ LPlo,
    const float* __restrict__ LPshi, const float* __restrict__ LPslo,
    const float* __restrict__ CThi, const float* __restrict__ CTlo,
    const float* __restrict__ CTshi, const float* __restrict__ CTslo,
    float* __restrict__ out) {
  int tid = threadIdx.x;
  int u = tid & 63;
  int wv = tid >> 6;
  int row = blockIdx.x * 4 + wv;    // [0, B*N)
  int b = row >> 12;                // 4096 rows per batch
  const float* fs = f2s + b * NN;
  float fv = f1[row];
  float theta = -fv;
  // lower_bound: first k with fs[k] >= theta  (12 = log2(4096) steps)
  int lo = 0, hiN = NN;
#pragma unroll
  for (int it = 0; it < 12; ++it) {
    int mid = (lo + hiN) >> 1;
    if (fs[mid] < theta) lo = mid + 1; else hiN = mid;
  }
  int t = lo;
  float e1 = expf(fv), e1l = expf(LEAKY * fv);
  float Phi = 0.f, Plo = 0.f, Pshi = 0.f, Pslo = 0.f;
  if (t > 0) {
    int c = (t - 1) >> 8;
    size_t lpidx = ((size_t)b * NN + (t - 1)) * NU + u;
    Phi = CThi[(size_t)(b * 17 + c) * NU + u] + LPhi[lpidx];
    Plo = CTlo[(size_t)(b * 17 + c) * NU + u] + LPlo[lpidx];
    Pshi = CTshi[b * 17 + c] + LPshi[b * NN + t - 1];
    Pslo = CTslo[b * 17 + c] + LPslo[b * NN + t - 1];
  }
  float Thi = CThi[(size_t)(b * 17 + 16) * NU + u];
  float Dtot = CTshi[b * 17 + 16];
  float Ahi = Thi - Phi;     // sum over k >= t of exp(f2)*h
  float Alo = Plo;           // sum over k <  t of exp(0.2 f2)*h
  float den = e1 * (Dtot - Pshi) + e1l * Pslo;
  float num = e1 * Ahi + e1l * Alo;
  out[(size_t)row * NU + u] = num / den;
}

// ---------------------------------------------------------------------------
extern "C" void kernel_launch(void* const* d_in, const int* in_sizes, int n_in,
                              void* d_out, int out_size, void* d_ws, size_t ws_size,
                              hipStream_t stream) {
  const float* x = (const float*)d_in[0];   // (4,4096,128) f32
  const float* W = (const float*)d_in[1];   // (128,64) f32
  const float* a = (const float*)d_in[2];   // (128,1) f32
  float* out = (float*)d_out;               // (4,4096,64) f32
  float* ws = (float*)d_ws;

  size_t o = 0;
  float* h    = ws + o; o += (size_t)NBATCH * NN * NU;
  float* f1   = ws + o; o += (size_t)NBATCH * NN;
  float* f2   = ws + o; o += (size_t)NBATCH * NN;
  int*  perm  = (int*)(ws + o); o += (size_t)NBATCH * NN;
  float* f2s  = ws + o; o += (size_t)NBATCH * NN;
  float* whi  = ws + o; o += (size_t)NBATCH * NN;
  float* wlo  = ws + o; o += (size_t)NBATCH * NN;
  float* LPhi = ws + o; o += (size_t)NBATCH * NN * NU;
  float* LPlo = ws + o; o += (size_t)NBATCH * NN * NU;
  float* LPshi= ws + o; o += (size_t)NBATCH * NN;
  float* LPslo= ws + o; o += (size_t)NBATCH * NN;
  float* CThi = ws + o; o += (size_t)NBATCH * 17 * NU;
  float* CTlo = ws + o; o += (size_t)NBATCH * 17 * NU;
  float* CTshi= ws + o; o += (size_t)NBATCH * 17;
  float* CTslo= ws + o; o += (size_t)NBATCH * 17;
  // total ~13.1 MB of ws

  k1_h<<<(NBATCH * NN) / 64, 256, 0, stream>>>(x, W, a, h, f1, f2);
  k2_rank<<<NBATCH * NCHUNK, 256, 0, stream>>>(f2, perm, f2s, whi, wlo);
  k3_scan<<<NBATCH * NCHUNK, 128, 0, stream>>>(h, perm, whi, wlo,
      LPhi, LPlo, LPshi, LPslo, CThi, CTlo, CTshi, CTslo);
  k3b_ct<<<1, 192, 0, stream>>>(CThi, CTlo, CTshi, CTslo);
  k4_out<<<(NBATCH * NN) / 4, 256, 0, stream>>>(f1, f2s,
      LPhi, LPlo, LPshi, LPslo, CThi, CTlo, CTshi, CTslo, out);
}

// Round 2
// 130.564 us; speedup vs baseline: 2.2003x; 2.2003x over previous
//
#include <hip/hip_runtime.h>
#include <hip/hip_bf16.h>

#define NBATCH 4
#define NN 4096
#define NF 128
#define NU 64
#define CHUNK 64
#define NCHUNK (NN / CHUNK)   // 64
#define LEAKY 0.2f

// ---------------------------------------------------------------------------
// k1: h[b,n,u] = sum_f x[b,n,f] * W[f,u];  f1 = h.a1, f2 = h.a2 (wave reduce)
// block = 256 threads (4 waves), 64 rows per block
// ---------------------------------------------------------------------------
__global__ __launch_bounds__(256) void k1_h(
    const float* __restrict__ x, const float* __restrict__ W,
    const float* __restrict__ a,
    float* __restrict__ h, float* __restrict__ f1, float* __restrict__ f2) {
  __shared__ float Ws[NF][NU];   // 32 KB
  __shared__ float xs[64][NF];   // 32 KB
  __shared__ float a1s[NU], a2s[NU];
  int tid = threadIdx.x;
  for (int k = tid; k < NF * NU; k += 256) ((float*)Ws)[k] = W[k];
  if (tid < NU) { a1s[tid] = a[tid]; a2s[tid] = a[NU + tid]; }
  int row0 = blockIdx.x * 64;   // flat row in [0, B*N)
  for (int k = tid; k < 64 * NF; k += 256)
    ((float*)xs)[k] = x[(size_t)row0 * NF + k];
  __syncthreads();
  int u = tid & 63;
  int wv = tid >> 6;            // wave id 0..3
  for (int rr = 0; rr < 16; ++rr) {
    int lr = wv * 16 + rr;
    float acc = 0.f;
#pragma unroll
    for (int f = 0; f < NF; f += 4) {
      float4 xv = *(const float4*)&xs[lr][f];   // broadcast ds_read_b128
      acc += xv.x * Ws[f][u] + xv.y * Ws[f + 1][u]
           + xv.z * Ws[f + 2][u] + xv.w * Ws[f + 3][u];
    }
    int grow = row0 + lr;
    h[(size_t)grow * NU + u] = acc;
    float p1 = acc * a1s[u], p2 = acc * a2s[u];
#pragma unroll
    for (int off = 32; off >= 1; off >>= 1) {
      p1 += __shfl_xor(p1, off, 64);
      p2 += __shfl_xor(p2, off, 64);
    }
    if (u == 0) { f1[grow] = p1; f2[grow] = p2; }
  }
}

// ---------------------------------------------------------------------------
// k2a: partial rank counts. block = (b, jchunk, kchunk) each 256 wide.
// pc[b][kc][j] = #{k in kc-chunk : f2[k] < f2[j] || (== && k<j)}
// ---------------------------------------------------------------------------
__global__ __launch_bounds__(256) void k2a_count(
    const float* __restrict__ f2, unsigned short* __restrict__ pc) {
  __shared__ float fsk[256];
  int b = blockIdx.x >> 8;          // 256 blocks per batch
  int jc = (blockIdx.x >> 4) & 15;
  int kc = blockIdx.x & 15;
  int tid = threadIdx.x;
  const float* f2b = f2 + b * NN;
  fsk[tid] = f2b[kc * 256 + tid];
  __syncthreads();
  int j = jc * 256 + tid;
  float my = f2b[j];
  int lim = j - kc * 256;           // k < lim  <=>  global k-index < j
  int cnt = 0;
#pragma unroll 8
  for (int k = 0; k < 256; ++k) {
    float v = fsk[k];
    cnt += (v < my) || (v == my && k < lim);
  }
  pc[((size_t)(b * 16 + kc)) * NN + j] = (unsigned short)cnt;
}

// ---------------------------------------------------------------------------
// k2b: rank = sum of 16 partials; scatter sorted f2, exp weights, perm.
// ---------------------------------------------------------------------------
__global__ __launch_bounds__(256) void k2b_scatter(
    const float* __restrict__ f2, const unsigned short* __restrict__ pc,
    int* __restrict__ perm, float* __restrict__ f2s,
    float* __restrict__ whi, float* __restrict__ wlo) {
  int b = blockIdx.x >> 4;
  int jc = blockIdx.x & 15;
  int j = jc * 256 + threadIdx.x;
  float my = f2[b * NN + j];
  int rank = 0;
#pragma unroll
  for (int kc = 0; kc < 16; ++kc)
    rank += pc[((size_t)(b * 16 + kc)) * NN + j];
  int o = b * NN + rank;
  perm[o] = j;
  f2s[o] = my;
  whi[o] = expf(my);
  wlo[o] = expf(LEAKY * my);
}

// ---------------------------------------------------------------------------
// k3: per-chunk (64 els) inclusive scan of
//   hi: sum_k exp(f2s[k]) * h[perm[k]][u]     (threads 0..63)
//   lo: sum_k exp(0.2 f2s[k]) * h[perm[k]][u] (threads 64..127)
// plus scalar denominators (lane u==0). Chunk totals -> CT.
// ---------------------------------------------------------------------------
__global__ __launch_bounds__(128) void k3_scan(
    const float* __restrict__ h, const int* __restrict__ perm,
    const float* __restrict__ whi, const float* __restrict__ wlo,
    float* __restrict__ LPhi, float* __restrict__ LPlo,
    float* __restrict__ LPshi, float* __restrict__ LPslo,
    float* __restrict__ CThi, float* __restrict__ CTlo,
    float* __restrict__ CTshi, float* __restrict__ CTslo) {
  __shared__ int pj[CHUNK];
  __shared__ float wh[CHUNK], wl[CHUNK];
  int b = blockIdx.x >> 6;          // NCHUNK=64 chunks per batch
  int chunk = blockIdx.x & 63;
  int k0 = b * NN + chunk * CHUNK;  // global sorted index base
  int tid = threadIdx.x;
  if (tid < CHUNK) {
    pj[tid] = perm[k0 + tid];
    wh[tid] = whi[k0 + tid];
    wl[tid] = wlo[k0 + tid];
  }
  __syncthreads();
  int u = tid & 63;
  bool hi = tid < 64;
  float* LP = hi ? LPhi : LPlo;
  float* LPs = hi ? LPshi : LPslo;
  const float* hb = h + (size_t)b * NN * NU;
  float acc = 0.f, sacc = 0.f;
  for (int k = 0; k < CHUNK; ++k) {
    float w = hi ? wh[k] : wl[k];
    int j = pj[k];
    acc += w * hb[(size_t)j * NU + u];
    LP[(size_t)(k0 + k) * NU + u] = acc;
    if (u == 0) { sacc += w; LPs[k0 + k] = sacc; }
  }
  float* CT = hi ? CThi : CTlo;
  CT[(size_t)(b * (NCHUNK + 1) + chunk) * NU + u] = acc;
  if (u == 0) (hi ? CTshi : CTslo)[b * (NCHUNK + 1) + chunk] = sacc;
}

// ---------------------------------------------------------------------------
// k3b: wave-parallel exclusive scan of the 64 chunk totals (lane = chunk).
// wid < 512: vector tables (b,half,u); wid in [512,520): scalar tables.
// ---------------------------------------------------------------------------
__global__ __launch_bounds__(256) void k3b_ct(
    float* __restrict__ CThi, float* __restrict__ CTlo,
    float* __restrict__ CTshi, float* __restrict__ CTslo) {
  int wid = blockIdx.x * 4 + (threadIdx.x >> 6);
  int lane = threadIdx.x & 63;   // = chunk index c
  if (wid < 512) {
    int b = wid >> 7;
    int half = (wid >> 6) & 1;
    int u = wid & 63;
    float* CT = (half == 0) ? CThi : CTlo;
    size_t idx = (size_t)(b * (NCHUNK + 1) + lane) * NU + u;
    float v = CT[idx];
#pragma unroll
    for (int off = 1; off < 64; off <<= 1) {
      float t = __shfl_up(v, off, 64);
      if (lane >= off) v += t;
    }
    float excl = __shfl_up(v, 1, 64);
    if (lane == 0) excl = 0.f;
    CT[idx] = excl;
    if (lane == 63) CT[(size_t)(b * (NCHUNK + 1) + NCHUNK) * NU + u] = v;
  } else if (wid < 520) {
    int s = wid - 512;
    int b = s >> 1;
    float* CTs = ((s & 1) == 0) ? CTshi : CTslo;
    float v = CTs[b * (NCHUNK + 1) + lane];
#pragma unroll
    for (int off = 1; off < 64; off <<= 1) {
      float t = __shfl_up(v, off, 64);
      if (lane >= off) v += t;
    }
    float excl = __shfl_up(v, 1, 64);
    if (lane == 0) excl = 0.f;
    CTs[b * (NCHUNK + 1) + lane] = excl;
    if (lane == 63) CTs[b * (NCHUNK + 1) + NCHUNK] = v;
  }
}

// ---------------------------------------------------------------------------
// k4: per output row: binary search threshold t, gather prefix rows, combine.
// block = 256 threads = 4 waves = 4 rows; lane u handles channel u.
// ---------------------------------------------------------------------------
__global__ __launch_bounds__(256) void k4_out(
    const float* __restrict__ f1, const float* __restrict__ f2s,
    const float* __restrict__ LPhi, const float* __restrict__ LPlo,
    const float* __restrict__ LPshi, const float* __restrict__ LPslo,
    const float* __restrict__ CThi, const float* __restrict__ CTlo,
    const float* __restrict__ CTshi, const float* __restrict__ CTslo,
    float* __restrict__ out) {
  int tid = threadIdx.x;
  int u = tid & 63;
  int wv = tid >> 6;
  int row = blockIdx.x * 4 + wv;    // [0, B*N)
  int b = row >> 12;                // 4096 rows per batch
  const float* fs = f2s + b * NN;
  float fv = f1[row];
  float theta = -fv;
  // lower_bound: first k with fs[k] >= theta
  int lo = 0, hiN = NN;
#pragma unroll
  for (int it = 0; it < 12; ++it) {
    int mid = (lo + hiN) >> 1;
    if (fs[mid] < theta) lo = mid + 1; else hiN = mid;
  }
  int t = lo;
  float e1 = expf(fv), e1l = expf(LEAKY * fv);
  float Phi = 0.f, Plo = 0.f, Pshi = 0.f, Pslo = 0.f;
  if (t > 0) {
    int c = (t - 1) >> 6;           // chunk of element t-1 (CHUNK=64)
    size_t ctidx = (size_t)(b * (NCHUNK + 1) + c) * NU + u;
    size_t lpidx = ((size_t)b * NN + (t - 1)) * NU + u;
    Phi = CThi[ctidx] + LPhi[lpidx];
    Plo = CTlo[ctidx] + LPlo[lpidx];
    Pshi = CTshi[b * (NCHUNK + 1) + c] + LPshi[b * NN + t - 1];
    Pslo = CTslo[b * (NCHUNK + 1) + c] + LPslo[b * NN + t - 1];
  }
  float Thi = CThi[(size_t)(b * (NCHUNK + 1) + NCHUNK) * NU + u];
  float Dtot = CTshi[b * (NCHUNK + 1) + NCHUNK];
  float Ahi = Thi - Phi;     // sum over k >= t of exp(f2)*h
  float Alo = Plo;           // sum over k <  t of exp(0.2 f2)*h
  float den = e1 * (Dtot - Pshi) + e1l * Pslo;
  float num = e1 * Ahi + e1l * Alo;
  out[(size_t)row * NU + u] = num / den;
}

// ---------------------------------------------------------------------------
extern "C" void kernel_launch(void* const* d_in, const int* in_sizes, int n_in,
                              void* d_out, int out_size, void* d_ws, size_t ws_size,
                              hipStream_t stream) {
  const float* x = (const float*)d_in[0];   // (4,4096,128) f32
  const float* W = (const float*)d_in[1];   // (128,64) f32
  const float* a = (const float*)d_in[2];   // (128,1) f32
  float* out = (float*)d_out;               // (4,4096,64) f32
  float* ws = (float*)d_ws;

  size_t o = 0;
  float* h    = ws + o; o += (size_t)NBATCH * NN * NU;
  float* f1   = ws + o; o += (size_t)NBATCH * NN;
  float* f2   = ws + o; o += (size_t)NBATCH * NN;
  int*  perm  = (int*)(ws + o); o += (size_t)NBATCH * NN;
  float* f2s  = ws + o; o += (size_t)NBATCH * NN;
  float* whi  = ws + o; o += (size_t)NBATCH * NN;
  float* wlo  = ws + o; o += (size_t)NBATCH * NN;
  float* LPhi = ws + o; o += (size_t)NBATCH * NN * NU;
  float* LPlo = ws + o; o += (size_t)NBATCH * NN * NU;
  float* LPshi= ws + o; o += (size_t)NBATCH * NN;
  float* LPslo= ws + o; o += (size_t)NBATCH * NN;
  float* CThi = ws + o; o += (size_t)NBATCH * (NCHUNK + 1) * NU;
  float* CTlo = ws + o; o += (size_t)NBATCH * (NCHUNK + 1) * NU;
  float* CTshi= ws + o; o += (size_t)NBATCH * (NCHUNK + 1);
  float* CTslo= ws + o; o += (size_t)NBATCH * (NCHUNK + 1);
  unsigned short* pc = (unsigned short*)(ws + o); o += (size_t)NBATCH * 16 * NN / 2;
  // total ~14 MB of ws

  k1_h<<<(NBATCH * NN) / 64, 256, 0, stream>>>(x, W, a, h, f1, f2);
  k2a_count<<<NBATCH * 256, 256, 0, stream>>>(f2, pc);
  k2b_scatter<<<NBATCH * 16, 256, 0, stream>>>(f2, pc, perm, f2s, whi, wlo);
  k3_scan<<<NBATCH * NCHUNK, 128, 0, stream>>>(h, perm, whi, wlo,
      LPhi, LPlo, LPshi, LPslo, CThi, CTlo, CTshi, CTslo);
  k3b_ct<<<130, 256, 0, stream>>>(CThi, CTlo, CTshi, CTslo);
  k4_out<<<(NBATCH * NN) / 4, 256, 0, stream>>>(f1, f2s,
      LPhi, LPlo, LPshi, LPslo, CThi, CTlo, CTshi, CTslo, out);
}

// Round 3
// 116.437 us; speedup vs baseline: 2.4672x; 1.1213x over previous
//
#include <hip/hip_runtime.h>
#include <hip/hip_bf16.h>

#define NBATCH 4
#define NN 4096
#define NF 128
#define NU 64
#define CH 32              // correction chunk length
#define NCH (NN / CH)      // 128 chunks per batch
#define LEAKY 0.2f

// ---------------------------------------------------------------------------
// k1: h[b,n,u] = sum_f x[b,n,f]*W[f,u]; f1 = h.a1, f2 = h.a2.
// 512 blocks x 256 thr; 32 rows/block; each wave owns 8 rows; lane = u.
// W read from global (L1/L2-hot, 128 loads/thread); x broadcast from LDS.
// ---------------------------------------------------------------------------
__global__ __launch_bounds__(256) void k1_h(
    const float* __restrict__ x, const float* __restrict__ W,
    const float* __restrict__ a,
    float* __restrict__ h, float* __restrict__ f1, float* __restrict__ f2) {
  __shared__ float xs[32][NF];   // 16 KB
  int tid = threadIdx.x;
  int row0 = blockIdx.x * 32;
  const float4* xg = (const float4*)(x + (size_t)row0 * NF);
  float4* xs4 = (float4*)xs;
  for (int k = tid; k < 32 * NF / 4; k += 256) xs4[k] = xg[k];
  __syncthreads();
  int u = tid & 63;
  int wv = tid >> 6;
  float acc[8] = {0.f,0.f,0.f,0.f,0.f,0.f,0.f,0.f};
#pragma unroll 4
  for (int f = 0; f < NF; f += 4) {
    float w0 = W[(f+0)*NU+u], w1 = W[(f+1)*NU+u],
          w2 = W[(f+2)*NU+u], w3 = W[(f+3)*NU+u];
#pragma unroll
    for (int r = 0; r < 8; ++r) {
      float4 xv = *(const float4*)&xs[wv*8+r][f];
      acc[r] += xv.x*w0 + xv.y*w1 + xv.z*w2 + xv.w*w3;
    }
  }
  float a1 = a[u], a2 = a[NU+u];
#pragma unroll
  for (int r = 0; r < 8; ++r) {
    int grow = row0 + wv*8 + r;
    h[(size_t)grow*NU+u] = acc[r];
    float p1 = acc[r]*a1, p2 = acc[r]*a2;
#pragma unroll
    for (int off = 32; off >= 1; off >>= 1) {
      p1 += __shfl_xor(p1, off, 64);
      p2 += __shfl_xor(p2, off, 64);
    }
    if (u == 0) { f1[grow] = p1; f2[grow] = p2; }
  }
}

// ---------------------------------------------------------------------------
// k2a: partial rank counts over (b, jchunk, kchunk) 256x256 tiles.
// ---------------------------------------------------------------------------
__global__ __launch_bounds__(256) void k2a_count(
    const float* __restrict__ f2, unsigned short* __restrict__ pc) {
  __shared__ float fsk[256];
  int b = blockIdx.x >> 8;
  int jc = (blockIdx.x >> 4) & 15;
  int kc = blockIdx.x & 15;
  int tid = threadIdx.x;
  const float* f2b = f2 + b * NN;
  fsk[tid] = f2b[kc * 256 + tid];
  __syncthreads();
  int j = jc * 256 + tid;
  float my = f2b[j];
  int lim = j - kc * 256;           // k < lim  <=>  global k-index < j
  int cnt = 0;
#pragma unroll 8
  for (int k = 0; k < 256; ++k) {
    float v = fsk[k];
    cnt += (v < my) || (v == my && k < lim);
  }
  pc[((size_t)(b * 16 + kc)) * NN + j] = (unsigned short)cnt;
}

// ---------------------------------------------------------------------------
// k2b: rank = sum of 16 partials; scatter sorted f2, exp weights, perm.
// ---------------------------------------------------------------------------
__global__ __launch_bounds__(256) void k2b_scatter(
    const float* __restrict__ f2, const unsigned short* __restrict__ pc,
    int* __restrict__ perm, float* __restrict__ f2s,
    float* __restrict__ whi, float* __restrict__ wlo) {
  int b = blockIdx.x >> 4;
  int jc = blockIdx.x & 15;
  int j = jc * 256 + threadIdx.x;
  float my = f2[b * NN + j];
  int rank = 0;
#pragma unroll
  for (int kc = 0; kc < 16; ++kc)
    rank += pc[((size_t)(b * 16 + kc)) * NN + j];
  int o = b * NN + rank;
  perm[o] = j;
  f2s[o] = my;
  whi[o] = expf(my);
  wlo[o] = expf(LEAKY * my);
}

// ---------------------------------------------------------------------------
// k3: chunk sums (no element-wise scan). One wave per chunk of 32 sorted els.
//   Pvhi[b][c][u] = sum_k exp(f2s)*h[perm][u],  Pvlo with exp(0.2*f2s)
//   Pshi/Pslo scalar sums. 128 blocks x 4 waves.
// ---------------------------------------------------------------------------
__global__ __launch_bounds__(256) void k3_csum(
    const float* __restrict__ h, const int* __restrict__ perm,
    const float* __restrict__ whi, const float* __restrict__ wlo,
    float* __restrict__ Pvhi, float* __restrict__ Pvlo,
    float* __restrict__ Pshi, float* __restrict__ Pslo) {
  int u = threadIdx.x & 63;
  int wv = threadIdx.x >> 6;
  int cg = blockIdx.x * 4 + wv;     // global chunk 0..511
  int b = cg >> 7;
  int c = cg & (NCH - 1);
  int k0 = b * NN + c * CH;
  const float* hb = h + (size_t)b * NN * NU;
  float ah = 0.f, al = 0.f, sh = 0.f, sl = 0.f;
#pragma unroll
  for (int k = 0; k < CH; ++k) {
    int j = perm[k0 + k];
    float wh = whi[k0 + k], wl = wlo[k0 + k];
    float hv = hb[(size_t)j * NU + u];
    ah += wh * hv; al += wl * hv; sh += wh; sl += wl;
  }
  size_t o = (size_t)(b * (NCH + 1) + c) * NU + u;
  Pvhi[o] = ah; Pvlo[o] = al;
  if (u == 0) { Pshi[b * (NCH + 1) + c] = sh; Pslo[b * (NCH + 1) + c] = sl; }
}

// ---------------------------------------------------------------------------
// k3b: in-place exclusive shuffle-scan of 128 chunk sums (2 per lane);
// slot [NCH] = total. wid<512: vector tables; wid in [512,520): scalars.
// ---------------------------------------------------------------------------
__global__ __launch_bounds__(256) void k3b_scan(
    float* __restrict__ Pvhi, float* __restrict__ Pvlo,
    float* __restrict__ Pshi, float* __restrict__ Pslo) {
  int wid = blockIdx.x * 4 + (threadIdx.x >> 6);
  int l = threadIdx.x & 63;
  if (wid < 512) {
    int b = wid >> 7;
    int half = (wid >> 6) & 1;
    int u = wid & 63;
    float* T = half ? Pvlo : Pvhi;
    size_t i0 = (size_t)(b * (NCH + 1) + 2 * l) * NU + u;
    size_t i1 = (size_t)(b * (NCH + 1) + 2 * l + 1) * NU + u;
    float v0 = T[i0], v1 = T[i1];
    float pair = v0 + v1, s = pair;
#pragma unroll
    for (int off = 1; off < 64; off <<= 1) {
      float t = __shfl_up(s, off, 64);
      if (l >= off) s += t;
    }
    float excl = s - pair;
    T[i0] = excl;
    T[i1] = excl + v0;
    if (l == 63) T[(size_t)(b * (NCH + 1) + NCH) * NU + u] = s;
  } else if (wid < 520) {
    int s2 = wid - 512;
    int b = s2 >> 1;
    float* T = (s2 & 1) ? Pslo : Pshi;
    float v0 = T[b * (NCH + 1) + 2 * l], v1 = T[b * (NCH + 1) + 2 * l + 1];
    float pair = v0 + v1, s = pair;
#pragma unroll
    for (int off = 1; off < 64; off <<= 1) {
      float t = __shfl_up(s, off, 64);
      if (l >= off) s += t;
    }
    float excl = s - pair;
    T[b * (NCH + 1) + 2 * l] = excl;
    T[b * (NCH + 1) + 2 * l + 1] = excl + v0;
    if (l == 63) T[b * (NCH + 1) + NCH] = s;
  }
}

// ---------------------------------------------------------------------------
// k4: per row: fan-out lower_bound (2 rounds of ballot), chunk-table lookup,
// 32-iter exact correction over the straddling chunk, combine, write.
// 4096 blocks x 256 thr; wave = one output row; lane = u.
// ---------------------------------------------------------------------------
__global__ __launch_bounds__(256) void k4_out(
    const float* __restrict__ f1, const float* __restrict__ f2s,
    const float* __restrict__ h, const int* __restrict__ perm,
    const float* __restrict__ whi, const float* __restrict__ wlo,
    const float* __restrict__ Pvhi, const float* __restrict__ Pvlo,
    const float* __restrict__ Pshi, const float* __restrict__ Pslo,
    float* __restrict__ out) {
  int u = threadIdx.x & 63;
  int wv = threadIdx.x >> 6;
  int row = blockIdx.x * 4 + wv;    // [0, B*N)
  int b = row >> 12;
  const float* fs = f2s + b * NN;
  float fv = f1[row];
  float theta = -fv;
  // step 1: lane l tests block-l max (fs sorted ascending)
  float q1 = fs[u * 64 + 63];
  int n1 = __popcll(__ballot(q1 < theta));   // # blocks entirely < theta
  int t;
  if (n1 == 64) {
    t = NN;
  } else {
    float q2 = fs[n1 * 64 + u];
    t = n1 * 64 + __popcll(__ballot(q2 < theta));
  }
  int c = t >> 5; if (c > NCH - 1) c = NCH - 1;
  int k0 = b * NN + c * CH;
  const float* hb = h + (size_t)b * NN * NU;
  float ch = 0.f, cl = 0.f, csh = 0.f, csl = 0.f;
#pragma unroll
  for (int k = 0; k < CH; ++k) {
    int kg = c * CH + k;
    int j = perm[k0 + k];
    float hv = hb[(size_t)j * NU + u];
    float wh = whi[k0 + k], wl = wlo[k0 + k];
    bool hi = (kg >= t);
    float wH = hi ? wh : 0.f;
    float wL = hi ? 0.f : wl;
    ch += wH * hv; cl += wL * hv; csh += wH; csl += wL;
  }
  size_t base = (size_t)b * (NCH + 1);
  size_t oc0 = (base + c) * NU + u;
  size_t oc1 = (base + c + 1) * NU + u;
  size_t oT  = (base + NCH) * NU + u;
  float Ahi = (Pvhi[oT] - Pvhi[oc1]) + ch;
  float Alo = Pvlo[oc0] + cl;
  float Shi = (Pshi[base + NCH] - Pshi[base + c + 1]) + csh;
  float Slo = Pslo[base + c] + csl;
  float e1 = expf(fv), e1l = expf(LEAKY * fv);
  float den = e1 * Shi + e1l * Slo;
  out[(size_t)row * NU + u] = (e1 * Ahi + e1l * Alo) / den;
}

// ---------------------------------------------------------------------------
extern "C" void kernel_launch(void* const* d_in, const int* in_sizes, int n_in,
                              void* d_out, int out_size, void* d_ws, size_t ws_size,
                              hipStream_t stream) {
  const float* x = (const float*)d_in[0];   // (4,4096,128) f32
  const float* W = (const float*)d_in[1];   // (128,64) f32
  const float* a = (const float*)d_in[2];   // (128,1) f32
  float* out = (float*)d_out;               // (4,4096,64) f32
  float* ws = (float*)d_ws;

  size_t o = 0;
  float* h    = ws + o; o += (size_t)NBATCH * NN * NU;        // 4 MB
  float* f1   = ws + o; o += (size_t)NBATCH * NN;
  float* f2   = ws + o; o += (size_t)NBATCH * NN;
  int*  perm  = (int*)(ws + o); o += (size_t)NBATCH * NN;
  float* f2s  = ws + o; o += (size_t)NBATCH * NN;
  float* whi  = ws + o; o += (size_t)NBATCH * NN;
  float* wlo  = ws + o; o += (size_t)NBATCH * NN;
  float* Pvhi = ws + o; o += (size_t)NBATCH * (NCH + 1) * NU;
  float* Pvlo = ws + o; o += (size_t)NBATCH * (NCH + 1) * NU;
  float* Pshi = ws + o; o += (size_t)NBATCH * (NCH + 1);
  float* Pslo = ws + o; o += (size_t)NBATCH * (NCH + 1);
  unsigned short* pc = (unsigned short*)(ws + o); o += (size_t)NBATCH * 16 * NN / 2;
  // ~5.3 MB of ws

  k1_h<<<(NBATCH * NN) / 32, 256, 0, stream>>>(x, W, a, h, f1, f2);
  k2a_count<<<NBATCH * 256, 256, 0, stream>>>(f2, pc);
  k2b_scatter<<<NBATCH * 16, 256, 0, stream>>>(f2, pc, perm, f2s, whi, wlo);
  k3_csum<<<(NBATCH * NCH) / 4, 256, 0, stream>>>(h, perm, whi, wlo,
      Pvhi, Pvlo, Pshi, Pslo);
  k3b_scan<<<130, 256, 0, stream>>>(Pvhi, Pvlo, Pshi, Pslo);
  k4_out<<<(NBATCH * NN) / 4, 256, 0, stream>>>(f1, f2s, h, perm, whi, wlo,
      Pvhi, Pvlo, Pshi, Pslo, out);
}

// Round 4
// 108.177 us; speedup vs baseline: 2.6556x; 1.0764x over previous
//
#include <hip/hip_runtime.h>
#include <hip/hip_bf16.h>

#define NBATCH 4
#define NN 4096
#define NF 128
#define NU 64
#define CH 16              // correction chunk length
#define NCH (NN / CH)      // 256 chunks per batch
#define LEAKY 0.2f

// ---------------------------------------------------------------------------
// k1: h[b,n,u] = sum_f x[b,n,f]*W[f,u]; f1 = h.a1, f2 = h.a2.
// 1024 blocks x 256 thr; 16 rows/block; wave owns 4 rows; lane = u.
// W from global (L1-hot, 32 KB shared chipwide); x broadcast from LDS.
// ---------------------------------------------------------------------------
__global__ __launch_bounds__(256) void k1_h(
    const float* __restrict__ x, const float* __restrict__ W,
    const float* __restrict__ a,
    float* __restrict__ h, float* __restrict__ f1, float* __restrict__ f2) {
  __shared__ float xs[16][NF];   // 8 KB
  int tid = threadIdx.x;
  int row0 = blockIdx.x * 16;
  const float4* xg = (const float4*)(x + (size_t)row0 * NF);
  float4* xs4 = (float4*)xs;
  for (int k = tid; k < 16 * NF / 4; k += 256) xs4[k] = xg[k];
  __syncthreads();
  int u = tid & 63;
  int wv = tid >> 6;
  float acc[4] = {0.f, 0.f, 0.f, 0.f};
#pragma unroll 4
  for (int f = 0; f < NF; f += 4) {
    float w0 = W[(f+0)*NU+u], w1 = W[(f+1)*NU+u],
          w2 = W[(f+2)*NU+u], w3 = W[(f+3)*NU+u];
#pragma unroll
    for (int r = 0; r < 4; ++r) {
      float4 xv = *(const float4*)&xs[wv*4+r][f];
      acc[r] += xv.x*w0 + xv.y*w1 + xv.z*w2 + xv.w*w3;
    }
  }
  float a1 = a[u], a2 = a[NU+u];
#pragma unroll
  for (int r = 0; r < 4; ++r) {
    int grow = row0 + wv*4 + r;
    h[(size_t)grow*NU+u] = acc[r];
    float p1 = acc[r]*a1, p2 = acc[r]*a2;
#pragma unroll
    for (int off = 32; off >= 1; off >>= 1) {
      p1 += __shfl_xor(p1, off, 64);
      p2 += __shfl_xor(p2, off, 64);
    }
    if (u == 0) { f1[grow] = p1; f2[grow] = p2; }
  }
}

// ---------------------------------------------------------------------------
// k2a: partial rank counts over (b, jchunk, kchunk) 256x256 tiles.
// ---------------------------------------------------------------------------
__global__ __launch_bounds__(256) void k2a_count(
    const float* __restrict__ f2, unsigned short* __restrict__ pc) {
  __shared__ float fsk[256];
  int b = blockIdx.x >> 8;
  int jc = (blockIdx.x >> 4) & 15;
  int kc = blockIdx.x & 15;
  int tid = threadIdx.x;
  const float* f2b = f2 + b * NN;
  fsk[tid] = f2b[kc * 256 + tid];
  __syncthreads();
  int j = jc * 256 + tid;
  float my = f2b[j];
  int lim = j - kc * 256;           // k < lim  <=>  global k-index < j
  int cnt = 0;
#pragma unroll 8
  for (int k = 0; k < 256; ++k) {
    float v = fsk[k];
    cnt += (v < my) || (v == my && k < lim);
  }
  pc[((size_t)(b * 16 + kc)) * NN + j] = (unsigned short)cnt;
}

// ---------------------------------------------------------------------------
// k2b: rank = sum of 16 partials; scatter packed {f2, e^f2, e^.2f2, perm}
// plus a plain sorted-f2 array for the k4 search.
// ---------------------------------------------------------------------------
__global__ __launch_bounds__(256) void k2b_scatter(
    const float* __restrict__ f2, const unsigned short* __restrict__ pc,
    float4* __restrict__ sdat, float* __restrict__ f2s) {
  int b = blockIdx.x >> 4;
  int jc = blockIdx.x & 15;
  int j = jc * 256 + threadIdx.x;
  float my = f2[b * NN + j];
  int rank = 0;
#pragma unroll
  for (int kc = 0; kc < 16; ++kc)
    rank += pc[((size_t)(b * 16 + kc)) * NN + j];
  int o = b * NN + rank;
  float4 v;
  v.x = my; v.y = expf(my); v.z = expf(LEAKY * my); v.w = __int_as_float(j);
  sdat[o] = v;
  f2s[o] = my;
}

// ---------------------------------------------------------------------------
// k3: chunk sums. One wave per chunk of CH=16 sorted els; lane = u.
// 256 blocks x 4 waves.
// ---------------------------------------------------------------------------
__global__ __launch_bounds__(256) void k3_csum(
    const float* __restrict__ h, const float4* __restrict__ sdat,
    float* __restrict__ Pvhi, float* __restrict__ Pvlo,
    float* __restrict__ Pshi, float* __restrict__ Pslo) {
  int u = threadIdx.x & 63;
  int wv = threadIdx.x >> 6;
  int cg = blockIdx.x * 4 + wv;     // global chunk 0..1023
  int b = cg >> 8;                  // 256 chunks per batch
  int c = cg & (NCH - 1);
  int k0 = b * NN + c * CH;
  const float* hb = h + (size_t)b * NN * NU;
  float ah = 0.f, al = 0.f, sh = 0.f, sl = 0.f;
#pragma unroll
  for (int k = 0; k < CH; ++k) {
    float4 e = sdat[k0 + k];
    int j = __float_as_int(e.w);
    float hv = hb[(size_t)j * NU + u];
    ah += e.y * hv; al += e.z * hv; sh += e.y; sl += e.z;
  }
  size_t o = (size_t)(b * (NCH + 1) + c) * NU + u;
  Pvhi[o] = ah; Pvlo[o] = al;
  if (u == 0) { Pshi[b * (NCH + 1) + c] = sh; Pslo[b * (NCH + 1) + c] = sl; }
}

// ---------------------------------------------------------------------------
// k3b: in-place exclusive shuffle-scan of NCH=256 chunk sums (4 per lane);
// slot [NCH] = total. wid<512: vector tables; wid in [512,520): scalars.
// ---------------------------------------------------------------------------
__global__ __launch_bounds__(256) void k3b_scan(
    float* __restrict__ Pvhi, float* __restrict__ Pvlo,
    float* __restrict__ Pshi, float* __restrict__ Pslo) {
  int wid = blockIdx.x * 4 + (threadIdx.x >> 6);
  int l = threadIdx.x & 63;
  if (wid < 512) {
    int b = wid >> 7;
    int half = (wid >> 6) & 1;
    int u = wid & 63;
    float* T = half ? Pvlo : Pvhi;
    size_t i0 = (size_t)(b * (NCH + 1) + 4 * l) * NU + u;
    float v0 = T[i0], v1 = T[i0 + NU], v2 = T[i0 + 2*NU], v3 = T[i0 + 3*NU];
    float lsum = v0 + v1 + v2 + v3, s = lsum;
#pragma unroll
    for (int off = 1; off < 64; off <<= 1) {
      float t = __shfl_up(s, off, 64);
      if (l >= off) s += t;
    }
    float e = s - lsum;            // exclusive prefix of this lane's chunks
    T[i0] = e;
    T[i0 + NU] = e + v0;
    T[i0 + 2*NU] = e + v0 + v1;
    T[i0 + 3*NU] = e + v0 + v1 + v2;
    if (l == 63) T[(size_t)(b * (NCH + 1) + NCH) * NU + u] = s;
  } else if (wid < 520) {
    int s2 = wid - 512;
    int b = s2 >> 1;
    float* T = (s2 & 1) ? Pslo : Pshi;
    int i0 = b * (NCH + 1) + 4 * l;
    float v0 = T[i0], v1 = T[i0 + 1], v2 = T[i0 + 2], v3 = T[i0 + 3];
    float lsum = v0 + v1 + v2 + v3, s = lsum;
#pragma unroll
    for (int off = 1; off < 64; off <<= 1) {
      float t = __shfl_up(s, off, 64);
      if (l >= off) s += t;
    }
    float e = s - lsum;
    T[i0] = e; T[i0 + 1] = e + v0; T[i0 + 2] = e + v0 + v1;
    T[i0 + 3] = e + v0 + v1 + v2;
    if (l == 63) T[b * (NCH + 1) + NCH] = s;
  }
}

// ---------------------------------------------------------------------------
// k4: per row: 2-round ballot lower_bound, chunk-table lookup, CH=16 exact
// correction over the straddling chunk, combine, write. wave = row; lane = u.
// ---------------------------------------------------------------------------
__global__ __launch_bounds__(256) void k4_out(
    const float* __restrict__ f1, const float* __restrict__ f2s,
    const float* __restrict__ h, const float4* __restrict__ sdat,
    const float* __restrict__ Pvhi, const float* __restrict__ Pvlo,
    const float* __restrict__ Pshi, const float* __restrict__ Pslo,
    float* __restrict__ out) {
  int u = threadIdx.x & 63;
  int wv = threadIdx.x >> 6;
  int row = blockIdx.x * 4 + wv;    // [0, B*N)
  int b = row >> 12;
  const float* fs = f2s + b * NN;
  float fv = f1[row];
  float theta = -fv;
  // fan-out lower_bound: first t with fs[t] >= theta
  float q1 = fs[u * 64 + 63];
  int n1 = __popcll(__ballot(q1 < theta));   // # 64-blocks entirely < theta
  int t;
  if (n1 == 64) {
    t = NN;
  } else {
    float q2 = fs[n1 * 64 + u];
    t = n1 * 64 + __popcll(__ballot(q2 < theta));
  }
  int c = t >> 4; if (c > NCH - 1) c = NCH - 1;
  int k0 = b * NN + c * CH;
  const float* hb = h + (size_t)b * NN * NU;
  float ch = 0.f, cl = 0.f, csh = 0.f, csl = 0.f;
#pragma unroll
  for (int k = 0; k < CH; ++k) {
    int kg = c * CH + k;
    float4 e = sdat[k0 + k];
    int j = __float_as_int(e.w);
    float hv = hb[(size_t)j * NU + u];
    bool hi = (kg >= t);
    float wH = hi ? e.y : 0.f;
    float wL = hi ? 0.f : e.z;
    ch += wH * hv; cl += wL * hv; csh += wH; csl += wL;
  }
  size_t base = (size_t)b * (NCH + 1);
  size_t oc0 = (base + c) * NU + u;
  size_t oc1 = (base + c + 1) * NU + u;
  size_t oT  = (base + NCH) * NU + u;
  float Ahi = (Pvhi[oT] - Pvhi[oc1]) + ch;
  float Alo = Pvlo[oc0] + cl;
  float Shi = (Pshi[base + NCH] - Pshi[base + c + 1]) + csh;
  float Slo = Pslo[base + c] + csl;
  float e1 = expf(fv), e1l = expf(LEAKY * fv);
  float den = e1 * Shi + e1l * Slo;
  out[(size_t)row * NU + u] = (e1 * Ahi + e1l * Alo) / den;
}

// ---------------------------------------------------------------------------
extern "C" void kernel_launch(void* const* d_in, const int* in_sizes, int n_in,
                              void* d_out, int out_size, void* d_ws, size_t ws_size,
                              hipStream_t stream) {
  const float* x = (const float*)d_in[0];   // (4,4096,128) f32
  const float* W = (const float*)d_in[1];   // (128,64) f32
  const float* a = (const float*)d_in[2];   // (128,1) f32
  float* out = (float*)d_out;               // (4,4096,64) f32
  float* ws = (float*)d_ws;

  size_t o = 0;
  float* h    = ws + o; o += (size_t)NBATCH * NN * NU;        // 4 MB
  float* f1   = ws + o; o += (size_t)NBATCH * NN;
  float* f2   = ws + o; o += (size_t)NBATCH * NN;
  float* f2s  = ws + o; o += (size_t)NBATCH * NN;
  float4* sdat = (float4*)(ws + o); o += (size_t)NBATCH * NN * 4;  // 16B aligned
  float* Pvhi = ws + o; o += (size_t)NBATCH * (NCH + 1) * NU;
  float* Pvlo = ws + o; o += (size_t)NBATCH * (NCH + 1) * NU;
  float* Pshi = ws + o; o += (size_t)NBATCH * (NCH + 1);
  float* Pslo = ws + o; o += (size_t)NBATCH * (NCH + 1);
  unsigned short* pc = (unsigned short*)(ws + o); o += (size_t)NBATCH * 16 * NN / 2;
  // ~6 MB of ws

  k1_h<<<(NBATCH * NN) / 16, 256, 0, stream>>>(x, W, a, h, f1, f2);
  k2a_count<<<NBATCH * 256, 256, 0, stream>>>(f2, pc);
  k2b_scatter<<<NBATCH * 16, 256, 0, stream>>>(f2, pc, sdat, f2s);
  k3_csum<<<(NBATCH * NCH) / 4, 256, 0, stream>>>(h, sdat, Pvhi, Pvlo, Pshi, Pslo);
  k3b_scan<<<130, 256, 0, stream>>>(Pvhi, Pvlo, Pshi, Pslo);
  k4_out<<<(NBATCH * NN) / 4, 256, 0, stream>>>(f1, f2s, h, sdat,
      Pvhi, Pvlo, Pshi, Pslo, out);
}